// Round 2
// baseline (22542.114 us; speedup 1.0000x reference)
//
#include <hip/hip_runtime.h>
#include <cstddef>

#define SEQ 2048
#define BB 2
#define DIM 768
#define NH 12
#define DH 64
#define WIN 256
#define NL 12
#define FFD 3072
#define HID2 512
#define HALF2 256

__device__ __forceinline__ float sigm(float x) { return 1.f / (1.f + expf(-x)); }
__device__ __forceinline__ float gelu_f(float x) {
    float x3 = x * x * x;
    return 0.5f * x * (1.f + tanhf(0.7978845608028654f * (x + 0.044715f * x3)));
}

__device__ __forceinline__ float wred_max(float v) {
    #pragma unroll
    for (int o = 32; o; o >>= 1) v = fmaxf(v, __shfl_xor(v, o));
    return v;
}
__device__ __forceinline__ float wred_sum(float v) {
    #pragma unroll
    for (int o = 32; o; o >>= 1) v += __shfl_xor(v, o);
    return v;
}

__device__ float block_sum256(float v, float* red) {
    int t = threadIdx.x;
    red[t] = v; __syncthreads();
    for (int s = 128; s > 0; s >>= 1) { if (t < s) red[t] += red[t + s]; __syncthreads(); }
    float r = red[0]; __syncthreads();
    return r;
}
__device__ float block_max256(float v, float* red) {
    int t = threadIdx.x;
    red[t] = v; __syncthreads();
    for (int s = 128; s > 0; s >>= 1) { if (t < s) red[t] = fmaxf(red[t], red[t + s]); __syncthreads(); }
    float r = red[0]; __syncthreads();
    return r;
}

// ---------------- GEMM: C[M,N] = A[M,K] @ B + bias, epilogue ----
// BT=0: B is K x N row-major.  BT=1: B is N x K row-major (C = A * B^T).
// EPI: 0 none, 1 gelu, 2 relu
template<int BT, int EPI>
__global__ __launch_bounds__(256) void gemm_k(const float* __restrict__ A,
                                              const float* __restrict__ Bm,
                                              const float* __restrict__ b1,
                                              const float* __restrict__ b2,
                                              float* __restrict__ C,
                                              int M, int N, int K) {
    __shared__ __align__(16) float As[16][68];
    __shared__ __align__(16) float Bs[16][68];
    const int tid = threadIdx.x;
    const int tx = tid & 15, ty = tid >> 4;
    const int col0 = blockIdx.x * 64;
    const int row0 = blockIdx.y * 64;
    float acc[4][4] = {};
    for (int k0 = 0; k0 < K; k0 += 16) {
        #pragma unroll
        for (int i = 0; i < 4; ++i) {
            int e = tid + 256 * i;
            int r = e >> 4, c = e & 15;
            As[c][r] = A[(size_t)(row0 + r) * K + k0 + c];
        }
        #pragma unroll
        for (int i = 0; i < 4; ++i) {
            int e = tid + 256 * i;
            if (BT == 0) {
                int kr = e >> 6, c = e & 63;
                Bs[kr][c] = Bm[(size_t)(k0 + kr) * N + col0 + c];
            } else {
                int kr = e & 15, c = e >> 4;
                Bs[kr][c] = Bm[(size_t)(col0 + c) * K + k0 + kr];
            }
        }
        __syncthreads();
        #pragma unroll
        for (int k = 0; k < 16; ++k) {
            float4 av = *(const float4*)&As[k][ty * 4];
            float4 bv = *(const float4*)&Bs[k][tx * 4];
            float am[4] = {av.x, av.y, av.z, av.w};
            float bn[4] = {bv.x, bv.y, bv.z, bv.w};
            #pragma unroll
            for (int i = 0; i < 4; ++i)
                #pragma unroll
                for (int j = 0; j < 4; ++j)
                    acc[i][j] += am[i] * bn[j];
        }
        __syncthreads();
    }
    float bias[4];
    #pragma unroll
    for (int j = 0; j < 4; ++j) {
        int n = col0 + tx * 4 + j;
        bias[j] = (b1 ? b1[n] : 0.f) + (b2 ? b2[n] : 0.f);
    }
    #pragma unroll
    for (int i = 0; i < 4; ++i) {
        int m = row0 + ty * 4 + i;
        float4 o;
        float vv[4];
        #pragma unroll
        for (int j = 0; j < 4; ++j) {
            float v = acc[i][j] + bias[j];
            if (EPI == 1) v = gelu_f(v);
            if (EPI == 2) v = fmaxf(v, 0.f);
            vv[j] = v;
        }
        o.x = vv[0]; o.y = vv[1]; o.z = vv[2]; o.w = vv[3];
        *(float4*)&C[(size_t)m * N + col0 + tx * 4] = o;
    }
}

// ---------------- embedding + LN ----------------
__global__ __launch_bounds__(256) void embed_k(const int* __restrict__ sent,
                                               const float* __restrict__ we,
                                               const float* __restrict__ pe,
                                               const float* __restrict__ gs,
                                               const float* __restrict__ gb,
                                               float* __restrict__ X) {
    __shared__ float red[256];
    int row = blockIdx.x, t = threadIdx.x;
    int tok = sent[row];
    int s = row & (SEQ - 1);
    float v[3];
    #pragma unroll
    for (int i = 0; i < 3; ++i) {
        int c = t + 256 * i;
        v[i] = we[(size_t)tok * DIM + c] + pe[(size_t)s * DIM + c];
    }
    float mean = block_sum256(v[0] + v[1] + v[2], red) * (1.f / DIM);
    float d0 = v[0] - mean, d1 = v[1] - mean, d2 = v[2] - mean;
    float var = block_sum256(d0 * d0 + d1 * d1 + d2 * d2, red) * (1.f / DIM);
    float rs = rsqrtf(var + 1e-5f);
    #pragma unroll
    for (int i = 0; i < 3; ++i) {
        int c = t + 256 * i;
        X[(size_t)row * DIM + c] = (v[i] - mean) * rs * gs[c] + gb[c];
    }
}

// ---------------- residual add + LN ----------------
__global__ __launch_bounds__(256) void resln_k(const float* __restrict__ A,
                                               const float* __restrict__ Bv,
                                               const float* __restrict__ gs,
                                               const float* __restrict__ gb,
                                               float* __restrict__ O) {
    __shared__ float red[256];
    int row = blockIdx.x, t = threadIdx.x;
    float v[3];
    #pragma unroll
    for (int i = 0; i < 3; ++i) {
        int c = t + 256 * i;
        v[i] = A[(size_t)row * DIM + c] + Bv[(size_t)row * DIM + c];
    }
    float mean = block_sum256(v[0] + v[1] + v[2], red) * (1.f / DIM);
    float d0 = v[0] - mean, d1 = v[1] - mean, d2 = v[2] - mean;
    float var = block_sum256(d0 * d0 + d1 * d1 + d2 * d2, red) * (1.f / DIM);
    float rs = rsqrtf(var + 1e-5f);
    #pragma unroll
    for (int i = 0; i < 3; ++i) {
        int c = t + 256 * i;
        O[(size_t)row * DIM + c] = (v[i] - mean) * rs * gs[c] + gb[c];
    }
}

// ---------------- sliding-window attention: one wave per query ----------------
__global__ __launch_bounds__(256) void attn_k(const float* __restrict__ Q,
                                              const float* __restrict__ Kb,
                                              const float* __restrict__ Vb,
                                              float* __restrict__ CTX) {
    __shared__ __align__(16) float wq[4][64];
    __shared__ float ps[4][576];
    int w = threadIdx.x >> 6, lane = threadIdx.x & 63;
    int qid = blockIdx.x * 4 + w;
    int sq = qid & (SEQ - 1);
    int bh = qid >> 11;
    int b = bh / NH, h = bh % NH;
    size_t qoff = ((size_t)(b * SEQ + sq)) * DIM + h * DH;
    wq[w][lane] = Q[qoff + lane] * 0.125f;  // 1/sqrt(64)
    __syncthreads();
    int jlo = sq - WIN; if (jlo < 0) jlo = 0;
    int jhi = sq + WIN; if (jhi > SEQ - 1) jhi = SEQ - 1;
    int count = jhi - jlo + 1;  // <= 513
    float sc[9];
    float m = -1e30f;
    #pragma unroll
    for (int t = 0; t < 9; ++t) {
        int idx = t * 64 + lane;
        float s = -1e30f;
        if (idx < count) {
            const float4* kp = (const float4*)(Kb + ((size_t)(b * SEQ + jlo + idx)) * DIM + h * DH);
            float acc = 0.f;
            #pragma unroll
            for (int dd = 0; dd < 16; ++dd) {
                float4 kv = kp[dd];
                float4 qv = *(const float4*)&wq[w][dd * 4];
                acc += qv.x * kv.x + qv.y * kv.y + qv.z * kv.z + qv.w * kv.w;
            }
            s = acc;
        }
        sc[t] = s;
        m = fmaxf(m, s);
    }
    m = wred_max(m);
    float lsum = 0.f;
    #pragma unroll
    for (int t = 0; t < 9; ++t) {
        int idx = t * 64 + lane;
        float e = 0.f;
        if (idx < count) { e = expf(sc[t] - m); lsum += e; }
        ps[w][idx] = e;
    }
    float denom = wred_sum(lsum);
    __syncthreads();
    float accd = 0.f;
    const float* vcol = Vb + ((size_t)(b * SEQ + jlo)) * DIM + h * DH + lane;
    for (int jj = 0; jj < count; ++jj)
        accd += ps[w][jj] * vcol[(size_t)jj * DIM];
    CTX[qoff + lane] = accd / denom;
}

// ---------------- LSTM gates ----------------
__global__ __launch_bounds__(256) void lstm_gate_k(const float* __restrict__ zx,
                                                   const float* __restrict__ zh,
                                                   const float* __restrict__ cin,
                                                   float* __restrict__ hout,
                                                   float* __restrict__ cout,
                                                   float* __restrict__ hcopy) {
    int idx = blockIdx.x * 256 + threadIdx.x;  // n*256+u
    int n = idx >> 8, u = idx & 255;
    size_t zb = (size_t)n * 1024;
    float zi = zx[zb + u], zf = zx[zb + 256 + u], zg = zx[zb + 512 + u], zo = zx[zb + 768 + u];
    if (zh) { zi += zh[zb + u]; zf += zh[zb + 256 + u]; zg += zh[zb + 512 + u]; zo += zh[zb + 768 + u]; }
    float cp = cin ? cin[idx] : 0.f;
    float c = sigm(zf) * cp + sigm(zi) * tanhf(zg);
    float hv = sigm(zo) * tanhf(c);
    hout[(size_t)n * 512 + u] = hv;
    cout[idx] = c;
    hcopy[idx] = hv;
}

// ---------------- attention pooling: energy = E1 @ pa_W2 + b2 ----------------
__global__ __launch_bounds__(256) void energy_k(const float* __restrict__ E1,
                                                const float* __restrict__ W2,
                                                const float* __restrict__ b2,
                                                float* __restrict__ EN) {
    int w = threadIdx.x >> 6, lane = threadIdx.x & 63;
    int r = blockIdx.x * 4 + w;
    float v = E1[(size_t)r * 64 + lane] * W2[lane];
    v = wred_sum(v);
    if (lane == 0) EN[r] = v + b2[0];
}

__global__ __launch_bounds__(256) void softmax_k(const float* __restrict__ EN,
                                                 float* __restrict__ WTS) {
    __shared__ float red[256];
    int b = blockIdx.x, t = threadIdx.x;
    const float* e = EN + (size_t)b * SEQ;
    float x[8];
    float m = -1e30f;
    #pragma unroll
    for (int i = 0; i < 8; ++i) { x[i] = e[t + 256 * i]; m = fmaxf(m, x[i]); }
    m = block_max256(m, red);
    float s = 0.f;
    #pragma unroll
    for (int i = 0; i < 8; ++i) { x[i] = expf(x[i] - m); s += x[i]; }
    s = block_sum256(s, red);
    float inv = 1.f / s;
    #pragma unroll
    for (int i = 0; i < 8; ++i) WTS[(size_t)b * SEQ + t + 256 * i] = x[i] * inv;
}

__global__ __launch_bounds__(512) void pooled_k(const float* __restrict__ WTS,
                                                const float* __restrict__ L1,
                                                float* __restrict__ P) {
    int b = blockIdx.x, d = threadIdx.x;
    const float* Lb = L1 + (size_t)b * SEQ * HID2;
    const float* wb = WTS + (size_t)b * SEQ;
    float acc = 0.f;
    for (int n = 0; n < SEQ; ++n) acc += wb[n] * Lb[(size_t)n * HID2 + d];
    P[b * HID2 + d] = acc;
}

// ---------------- tiny BiLSTM2 + tag head (single block) ----------------
__global__ __launch_bounds__(1024) void lstm2_k(const float* __restrict__ P,
                                                const float* __restrict__ Wih,
                                                const float* __restrict__ Whh,
                                                const float* __restrict__ bih,
                                                const float* __restrict__ bhh,
                                                const float* __restrict__ Wtag,
                                                const float* __restrict__ btag,
                                                float* __restrict__ out) {
    __shared__ float h[256], c[256], z[1024], flat2[1024], red[1024];
    int t = threadIdx.x;
    for (int dir = 0; dir < 2; ++dir) {
        if (t < 256) { h[t] = 0.f; c[t] = 0.f; }
        __syncthreads();
        for (int st = 0; st < 2; ++st) {
            int xt = (dir == 0) ? st : 1 - st;
            {
                int j = t;
                const float* wr = Wih + ((size_t)dir * 1024 + j) * HID2;
                const float* pr = P + xt * HID2;
                float acc = bih[dir * 1024 + j] + bhh[dir * 1024 + j];
                for (int k = 0; k < HID2; ++k) acc += pr[k] * wr[k];
                const float* wh = Whh + ((size_t)dir * 1024 + j) * HALF2;
                for (int k = 0; k < HALF2; ++k) acc += h[k] * wh[k];
                z[j] = acc;
            }
            __syncthreads();
            if (t < 256) {
                float zi = z[t], zf = z[256 + t], zg = z[512 + t], zo = z[768 + t];
                float cn = sigm(zf) * c[t] + sigm(zi) * tanhf(zg);
                float hn = sigm(zo) * tanhf(cn);
                c[t] = cn;
                h[t] = hn;
                int oidx = (dir == 0) ? (st * 512 + t) : ((1 - st) * 512 + 256 + t);
                flat2[oidx] = hn;
            }
            __syncthreads();
        }
    }
    for (int b = 0; b < 2; ++b) {
        float v = (t < 512) ? flat2[b * 512 + t] * Wtag[t] : 0.f;
        red[t] = v; __syncthreads();
        for (int s = 512; s > 0; s >>= 1) { if (t < s) red[t] += red[t + s]; __syncthreads(); }
        if (t == 0) out[b] = red[0] + btag[0];
        __syncthreads();
    }
}

extern "C" void kernel_launch(void* const* d_in, const int* in_sizes, int n_in,
                              void* d_out, int out_size, void* d_ws, size_t ws_size,
                              hipStream_t stream) {
    (void)in_sizes; (void)n_in; (void)out_size; (void)ws_size;
    const int* sent = (const int*)d_in[0];
    const float* word_emb = (const float*)d_in[1];
    const float* pos_emb  = (const float*)d_in[2];
    const float* emb_ln_s = (const float*)d_in[3];
    const float* emb_ln_b = (const float*)d_in[4];
    const float* Wq = (const float*)d_in[5];
    const float* Wk = (const float*)d_in[6];
    const float* Wv = (const float*)d_in[7];
    const float* Wo = (const float*)d_in[8];
    const float* bq = (const float*)d_in[9];
    const float* bk = (const float*)d_in[10];
    const float* bv = (const float*)d_in[11];
    const float* bo = (const float*)d_in[12];
    const float* ln1_s = (const float*)d_in[13];
    const float* ln1_b = (const float*)d_in[14];
    const float* Wf1 = (const float*)d_in[15];
    const float* bf1 = (const float*)d_in[16];
    const float* Wf2 = (const float*)d_in[17];
    const float* bf2 = (const float*)d_in[18];
    const float* ln2_s = (const float*)d_in[19];
    const float* ln2_b = (const float*)d_in[20];
    const float* l1_Wih = (const float*)d_in[21];
    const float* l1_Whh = (const float*)d_in[22];
    const float* l1_bih = (const float*)d_in[23];
    const float* l1_bhh = (const float*)d_in[24];
    const float* pa_W1 = (const float*)d_in[25];
    const float* pa_b1 = (const float*)d_in[26];
    const float* pa_W2 = (const float*)d_in[27];
    const float* pa_b2 = (const float*)d_in[28];
    const float* l2_Wih = (const float*)d_in[29];
    const float* l2_Whh = (const float*)d_in[30];
    const float* l2_bih = (const float*)d_in[31];
    const float* l2_bhh = (const float*)d_in[32];
    const float* Wtag = (const float*)d_in[33];
    const float* btag = (const float*)d_in[34];

    float* ws = (float*)d_ws;
    const size_t NX = (size_t)BB * SEQ * DIM;      // 3145728
    // Transformer phase layout (total 6*NX floats = 75.5 MB):
    float* X1  = ws;                 // x_mid
    float* Qb  = ws + NX * 1;        // Q / attn-out / FF2-out scratch
    float* X   = ws + NX * 2;        // layer input & output (residual stream)
    float* Kbf = ws + NX * 3;
    float* Vbf = ws + NX * 4;
    float* CTX = ws + NX * 5;
    float* FH  = ws + NX * 2;        // FF hidden (4096x3072) overlays [X,Kbf,Vbf,CTX],
                                     // all dead during FF1/FF2; X rewritten only after FH consumed
    // LSTM-phase overlay: X (at 2NX) still holds transformer output.
    float* XZF  = ws + NX * 3;                     // 4096x1024
    float* XZB  = XZF + (size_t)4096 * 1024;       // 4096x1024  (ends at 17.8M < 6NX)
    float* TMPZ = ws;                              // 2048x1024
    float* L1O  = TMPZ + (size_t)2048 * 1024;      // 2x2048x512
    float* HPV  = L1O + (size_t)2 * 2048 * 512;    // 2048x256
    float* CST  = HPV + (size_t)2048 * 256;        // 2048x256
    float* E1   = CST + (size_t)2048 * 256;        // 4096x64
    float* ENG  = E1 + (size_t)4096 * 64;          // 4096
    float* WTS  = ENG + 4096;                      // 4096
    float* PLD  = WTS + 4096;                      // 1024   (ends ~5.27M < 2NX)

    const int M = BB * SEQ;  // 4096

    embed_k<<<M, 256, 0, stream>>>(sent, word_emb, pos_emb, emb_ln_s, emb_ln_b, X);

    for (int l = 0; l < NL; ++l) {
        const float* Wq_l = Wq + (size_t)l * DIM * DIM;
        const float* Wk_l = Wk + (size_t)l * DIM * DIM;
        const float* Wv_l = Wv + (size_t)l * DIM * DIM;
        const float* Wo_l = Wo + (size_t)l * DIM * DIM;
        const float* Wf1_l = Wf1 + (size_t)l * DIM * FFD;
        const float* Wf2_l = Wf2 + (size_t)l * FFD * DIM;

        gemm_k<0, 0><<<dim3(DIM / 64, M / 64), 256, 0, stream>>>(X, Wq_l, bq + l * DIM, nullptr, Qb, M, DIM, DIM);
        gemm_k<0, 0><<<dim3(DIM / 64, M / 64), 256, 0, stream>>>(X, Wk_l, bk + l * DIM, nullptr, Kbf, M, DIM, DIM);
        gemm_k<0, 0><<<dim3(DIM / 64, M / 64), 256, 0, stream>>>(X, Wv_l, bv + l * DIM, nullptr, Vbf, M, DIM, DIM);

        attn_k<<<(BB * NH * SEQ) / 4, 256, 0, stream>>>(Qb, Kbf, Vbf, CTX);

        gemm_k<0, 0><<<dim3(DIM / 64, M / 64), 256, 0, stream>>>(CTX, Wo_l, bo + l * DIM, nullptr, Qb, M, DIM, DIM);
        resln_k<<<M, 256, 0, stream>>>(X, Qb, ln1_s + l * DIM, ln1_b + l * DIM, X1);

        gemm_k<0, 1><<<dim3(FFD / 64, M / 64), 256, 0, stream>>>(X1, Wf1_l, bf1 + l * FFD, nullptr, FH, M, FFD, DIM);
        gemm_k<0, 0><<<dim3(DIM / 64, M / 64), 256, 0, stream>>>(FH, Wf2_l, bf2 + l * DIM, nullptr, Qb, M, DIM, FFD);
        resln_k<<<M, 256, 0, stream>>>(X1, Qb, ln2_s + l * DIM, ln2_b + l * DIM, X);
    }

    // ---- BiLSTM over the 2-step batch axis ----
    gemm_k<1, 0><<<dim3(1024 / 64, M / 64), 256, 0, stream>>>(X, l1_Wih, l1_bih, l1_bhh, XZF, M, 1024, DIM);
    gemm_k<1, 0><<<dim3(1024 / 64, M / 64), 256, 0, stream>>>(X, l1_Wih + (size_t)1024 * DIM, l1_bih + 1024, l1_bhh + 1024, XZB, M, 1024, DIM);

    // forward dir: steps x[0], x[1]
    lstm_gate_k<<<2048, 256, 0, stream>>>(XZF, nullptr, nullptr, L1O + 0, CST, HPV);
    gemm_k<1, 0><<<dim3(1024 / 64, 2048 / 64), 256, 0, stream>>>(HPV, l1_Whh, nullptr, nullptr, TMPZ, 2048, 1024, 256);
    lstm_gate_k<<<2048, 256, 0, stream>>>(XZF + (size_t)2048 * 1024, TMPZ, CST, L1O + (size_t)1 * 2048 * 512, CST, HPV);
    // backward dir: steps x[1], x[0]; outputs reversed
    lstm_gate_k<<<2048, 256, 0, stream>>>(XZB + (size_t)2048 * 1024, nullptr, nullptr, L1O + (size_t)1 * 2048 * 512 + 256, CST, HPV);
    gemm_k<1, 0><<<dim3(1024 / 64, 2048 / 64), 256, 0, stream>>>(HPV, l1_Whh + (size_t)1024 * 256, nullptr, nullptr, TMPZ, 2048, 1024, 256);
    lstm_gate_k<<<2048, 256, 0, stream>>>(XZB, TMPZ, CST, L1O + 256, CST, HPV);

    // ---- attention pooling ----
    gemm_k<0, 2><<<dim3(64 / 64, M / 64), 256, 0, stream>>>(L1O, pa_W1, pa_b1, nullptr, E1, M, 64, HID2);
    energy_k<<<M / 4, 256, 0, stream>>>(E1, pa_W2, pa_b2, ENG);
    softmax_k<<<BB, 256, 0, stream>>>(ENG, WTS);
    pooled_k<<<BB, 512, 0, stream>>>(WTS, L1O, PLD);

    // ---- tiny BiLSTM2 + head ----
    lstm2_k<<<1, 1024, 0, stream>>>(PLD, l2_Wih, l2_Whh, l2_bih, l2_bhh, Wtag, btag, (float*)d_out);
}

// Round 4
// 8253.618 us; speedup vs baseline: 2.7312x; 2.7312x over previous
//
#include <hip/hip_runtime.h>
#include <cstddef>

#define SEQ 2048
#define BB 2
#define DIM 768
#define NH 12
#define DH 64
#define WIN 256
#define NL 12
#define FFD 3072
#define HID2 512
#define HALF2 256

typedef __bf16 bf16_8 __attribute__((ext_vector_type(8)));
typedef __bf16 bf16_4 __attribute__((ext_vector_type(4)));
typedef float floatx4 __attribute__((ext_vector_type(4)));

struct GP {
    const float* B[3];
    const float* b1[3];
    const float* b2[3];
    float* C[3];
};

__device__ __forceinline__ float sigm(float x) { return 1.f / (1.f + expf(-x)); }
__device__ __forceinline__ float gelu_f(float x) {
    float x3 = x * x * x;
    return 0.5f * x * (1.f + tanhf(0.7978845608028654f * (x + 0.044715f * x3)));
}

__device__ __forceinline__ __bf16 bfrn(float x) {
    unsigned u = __builtin_bit_cast(unsigned, x);
    u += 0x7FFFu + ((u >> 16) & 1u);
    unsigned short hs = (unsigned short)(u >> 16);
    return __builtin_bit_cast(__bf16, hs);
}
struct HL { __bf16 h, l; };
__device__ __forceinline__ HL split1(float x) {
    HL r;
    r.h = bfrn(x);
    r.l = bfrn(x - (float)r.h);
    return r;
}

__device__ __forceinline__ float wred_sum(float v) {
    #pragma unroll
    for (int o = 32; o; o >>= 1) v += __shfl_xor(v, o);
    return v;
}

__device__ float block_sum256(float v, float* red) {
    int t = threadIdx.x;
    red[t] = v; __syncthreads();
    for (int s = 128; s > 0; s >>= 1) { if (t < s) red[t] += red[t + s]; __syncthreads(); }
    float r = red[0]; __syncthreads();
    return r;
}
__device__ float block_max256(float v, float* red) {
    int t = threadIdx.x;
    red[t] = v; __syncthreads();
    for (int s = 128; s > 0; s >>= 1) { if (t < s) red[t] = fmaxf(red[t], red[t + s]); __syncthreads(); }
    float r = red[0]; __syncthreads();
    return r;
}

// ================= split-bf16 MFMA GEMM: C[M,N] = A @ B (+bias, EPI) =========
// BT=0: B is KxN row-major. BT=1: B is NxK row-major (C = A*B^T).
// EPI: 0 none, 1 gelu.  z = blockIdx.z selects pointer set in GP.
template<int BT, int EPI>
__global__ __launch_bounds__(256, 2) void gemm_mfma(const float* __restrict__ A,
                                                    GP p, int M, int N, int K) {
    __shared__ __bf16 Ah[128][56];
    __shared__ __bf16 Al[128][56];
    __shared__ __bf16 Bh[128][56];
    __shared__ __bf16 Bl[128][56];
    const int z = blockIdx.z;
    const float* __restrict__ Bm = p.B[z];
    const float* __restrict__ b1 = p.b1[z];
    const float* __restrict__ b2 = p.b2[z];
    float* __restrict__ C = p.C[z];
    const int t = threadIdx.x;
    const int col0 = blockIdx.x * 128, row0 = blockIdx.y * 128;
    const int sr = t >> 1;             // 0..127 (A / BT1 row)
    const int sk = (t & 1) * 16;       // 0/16
    const int bn = t & 127;            // BT0: n
    const int bk = (t >> 7) * 16;      // BT0: k base
    const int wv = t >> 6, lane = t & 63;
    const int wr = (wv >> 1) * 64, wc = (wv & 1) * 64;
    const int l15 = lane & 15, quad = lane >> 4;

    floatx4 acc[16];
    #pragma unroll
    for (int i = 0; i < 16; ++i) acc[i] = (floatx4)0.f;

    for (int k0 = 0; k0 < K; k0 += 32) {
        __syncthreads();
        {   // stage A
            const float* ap = A + (size_t)(row0 + sr) * K + k0 + sk;
            #pragma unroll
            for (int c = 0; c < 4; ++c) {
                float4 v = *(const float4*)(ap + c * 4);
                bf16_4 h, l;
                HL r0 = split1(v.x), r1 = split1(v.y), r2 = split1(v.z), r3 = split1(v.w);
                h[0] = r0.h; l[0] = r0.l; h[1] = r1.h; l[1] = r1.l;
                h[2] = r2.h; l[2] = r2.l; h[3] = r3.h; l[3] = r3.l;
                *(bf16_4*)&Ah[sr][sk + c * 4] = h;
                *(bf16_4*)&Al[sr][sk + c * 4] = l;
            }
        }
        if (BT == 1) {  // stage B (N x K, same pattern as A)
            const float* bp = Bm + (size_t)(col0 + sr) * K + k0 + sk;
            #pragma unroll
            for (int c = 0; c < 4; ++c) {
                float4 v = *(const float4*)(bp + c * 4);
                bf16_4 h, l;
                HL r0 = split1(v.x), r1 = split1(v.y), r2 = split1(v.z), r3 = split1(v.w);
                h[0] = r0.h; l[0] = r0.l; h[1] = r1.h; l[1] = r1.l;
                h[2] = r2.h; l[2] = r2.l; h[3] = r3.h; l[3] = r3.l;
                *(bf16_4*)&Bh[sr][sk + c * 4] = h;
                *(bf16_4*)&Bl[sr][sk + c * 4] = l;
            }
        } else {        // stage B (K x N) -> Bs[n][k] transpose-gather
            float v[16];
            const float* bp = Bm + (size_t)(k0 + bk) * N + col0 + bn;
            #pragma unroll
            for (int j = 0; j < 16; ++j) v[j] = bp[(size_t)j * N];
            #pragma unroll
            for (int c = 0; c < 4; ++c) {
                bf16_4 h, l;
                HL r0 = split1(v[4 * c + 0]), r1 = split1(v[4 * c + 1]);
                HL r2 = split1(v[4 * c + 2]), r3 = split1(v[4 * c + 3]);
                h[0] = r0.h; l[0] = r0.l; h[1] = r1.h; l[1] = r1.l;
                h[2] = r2.h; l[2] = r2.l; h[3] = r3.h; l[3] = r3.l;
                *(bf16_4*)&Bh[bn][bk + c * 4] = h;
                *(bf16_4*)&Bl[bn][bk + c * 4] = l;
            }
        }
        __syncthreads();
        bf16_8 ah[4], alo[4];
        #pragma unroll
        for (int rt = 0; rt < 4; ++rt) {
            ah[rt]  = *(const bf16_8*)&Ah[wr + rt * 16 + l15][quad * 8];
            alo[rt] = *(const bf16_8*)&Al[wr + rt * 16 + l15][quad * 8];
        }
        #pragma unroll
        for (int ct = 0; ct < 4; ++ct) {
            bf16_8 bh = *(const bf16_8*)&Bh[wc + ct * 16 + l15][quad * 8];
            bf16_8 bl = *(const bf16_8*)&Bl[wc + ct * 16 + l15][quad * 8];
            #pragma unroll
            for (int rt = 0; rt < 4; ++rt) {
                floatx4 a = acc[rt * 4 + ct];
                a = __builtin_amdgcn_mfma_f32_16x16x32_bf16(ah[rt], bh, a, 0, 0, 0);
                a = __builtin_amdgcn_mfma_f32_16x16x32_bf16(alo[rt], bh, a, 0, 0, 0);
                a = __builtin_amdgcn_mfma_f32_16x16x32_bf16(ah[rt], bl, a, 0, 0, 0);
                acc[rt * 4 + ct] = a;
            }
        }
    }
    #pragma unroll
    for (int ct = 0; ct < 4; ++ct) {
        int colg = col0 + wc + ct * 16 + l15;
        float bias = 0.f;
        if (b1) bias += b1[colg];
        if (b2) bias += b2[colg];
        #pragma unroll
        for (int rt = 0; rt < 4; ++rt) {
            floatx4 a = acc[rt * 4 + ct];
            int rowg = row0 + wr + rt * 16 + quad * 4;
            #pragma unroll
            for (int rg = 0; rg < 4; ++rg) {
                float vo = a[rg] + bias;
                if (EPI == 1) vo = gelu_f(vo);
                C[(size_t)(rowg + rg) * N + colg] = vo;
            }
        }
    }
}

// ---------------- small fp32 GEMM (kept for pa_W1, N=64) ----------------
template<int BT, int EPI>
__global__ __launch_bounds__(256) void gemm_k(const float* __restrict__ A,
                                              const float* __restrict__ Bm,
                                              const float* __restrict__ b1,
                                              const float* __restrict__ b2,
                                              float* __restrict__ C,
                                              int M, int N, int K) {
    __shared__ __align__(16) float As[16][68];
    __shared__ __align__(16) float Bs[16][68];
    const int tid = threadIdx.x;
    const int tx = tid & 15, ty = tid >> 4;
    const int col0 = blockIdx.x * 64;
    const int row0 = blockIdx.y * 64;
    float acc[4][4] = {};
    for (int k0 = 0; k0 < K; k0 += 16) {
        #pragma unroll
        for (int i = 0; i < 4; ++i) {
            int e = tid + 256 * i;
            int r = e >> 4, c = e & 15;
            As[c][r] = A[(size_t)(row0 + r) * K + k0 + c];
        }
        #pragma unroll
        for (int i = 0; i < 4; ++i) {
            int e = tid + 256 * i;
            if (BT == 0) {
                int kr = e >> 6, c = e & 63;
                Bs[kr][c] = Bm[(size_t)(k0 + kr) * N + col0 + c];
            } else {
                int kr = e & 15, c = e >> 4;
                Bs[kr][c] = Bm[(size_t)(col0 + c) * K + k0 + kr];
            }
        }
        __syncthreads();
        #pragma unroll
        for (int k = 0; k < 16; ++k) {
            float4 av = *(const float4*)&As[k][ty * 4];
            float4 bv = *(const float4*)&Bs[k][tx * 4];
            float am[4] = {av.x, av.y, av.z, av.w};
            float bn2[4] = {bv.x, bv.y, bv.z, bv.w};
            #pragma unroll
            for (int i = 0; i < 4; ++i)
                #pragma unroll
                for (int j = 0; j < 4; ++j)
                    acc[i][j] += am[i] * bn2[j];
        }
        __syncthreads();
    }
    float bias[4];
    #pragma unroll
    for (int j = 0; j < 4; ++j) {
        int n = col0 + tx * 4 + j;
        bias[j] = (b1 ? b1[n] : 0.f) + (b2 ? b2[n] : 0.f);
    }
    #pragma unroll
    for (int i = 0; i < 4; ++i) {
        int m = row0 + ty * 4 + i;
        float4 o;
        float vv[4];
        #pragma unroll
        for (int j = 0; j < 4; ++j) {
            float v = acc[i][j] + bias[j];
            if (EPI == 1) v = gelu_f(v);
            if (EPI == 2) v = fmaxf(v, 0.f);
            vv[j] = v;
        }
        o.x = vv[0]; o.y = vv[1]; o.z = vv[2]; o.w = vv[3];
        *(float4*)&C[(size_t)m * N + col0 + tx * 4] = o;
    }
}

// ---------------- embedding + LN ----------------
__global__ __launch_bounds__(256) void embed_k(const int* __restrict__ sent,
                                               const float* __restrict__ we,
                                               const float* __restrict__ pe,
                                               const float* __restrict__ gs,
                                               const float* __restrict__ gb,
                                               float* __restrict__ X) {
    __shared__ float red[256];
    int row = blockIdx.x, t = threadIdx.x;
    int tok = sent[row];
    int s = row & (SEQ - 1);
    float v[3];
    #pragma unroll
    for (int i = 0; i < 3; ++i) {
        int c = t + 256 * i;
        v[i] = we[(size_t)tok * DIM + c] + pe[(size_t)s * DIM + c];
    }
    float mean = block_sum256(v[0] + v[1] + v[2], red) * (1.f / DIM);
    float d0 = v[0] - mean, d1 = v[1] - mean, d2 = v[2] - mean;
    float var = block_sum256(d0 * d0 + d1 * d1 + d2 * d2, red) * (1.f / DIM);
    float rs = rsqrtf(var + 1e-5f);
    #pragma unroll
    for (int i = 0; i < 3; ++i) {
        int c = t + 256 * i;
        X[(size_t)row * DIM + c] = (v[i] - mean) * rs * gs[c] + gb[c];
    }
}

// ---------------- residual add + LN ----------------
__global__ __launch_bounds__(256) void resln_k(const float* __restrict__ A,
                                               const float* __restrict__ Bv,
                                               const float* __restrict__ gs,
                                               const float* __restrict__ gb,
                                               float* __restrict__ O) {
    __shared__ float red[256];
    int row = blockIdx.x, t = threadIdx.x;
    float v[3];
    #pragma unroll
    for (int i = 0; i < 3; ++i) {
        int c = t + 256 * i;
        v[i] = A[(size_t)row * DIM + c] + Bv[(size_t)row * DIM + c];
    }
    float mean = block_sum256(v[0] + v[1] + v[2], red) * (1.f / DIM);
    float d0 = v[0] - mean, d1 = v[1] - mean, d2 = v[2] - mean;
    float var = block_sum256(d0 * d0 + d1 * d1 + d2 * d2, red) * (1.f / DIM);
    float rs = rsqrtf(var + 1e-5f);
    #pragma unroll
    for (int i = 0; i < 3; ++i) {
        int c = t + 256 * i;
        O[(size_t)row * DIM + c] = (v[i] - mean) * rs * gs[c] + gb[c];
    }
}

// ======== block-tiled flash attention: 64 queries x 9 key-tiles of 64 ========
// grid: (SEQ/64, NH, BB), block 256
__global__ __launch_bounds__(256, 2) void attn2_k(const float* __restrict__ Q,
                                                  const float* __restrict__ Kb,
                                                  const float* __restrict__ Vb,
                                                  float* __restrict__ CTX) {
    __shared__ float Qt[64][68];   // [d][q], pre-scaled
    __shared__ float Ktt[64][68];  // [d][k]
    __shared__ float Vs[64][68];   // [k][d]
    __shared__ float Sb[64][68];   // [q][k]
    __shared__ float Pt[64][68];   // [k][q]
    __shared__ float mrow[64], lrow[64], arow[64];
    const int t = threadIdx.x;
    const int c0 = blockIdx.x * 64;
    const int h = blockIdx.y, b = blockIdx.z;
    const size_t base = ((size_t)b * SEQ) * DIM + h * DH;
    const int ty = t >> 4, tx = t & 15;

    {   // stage Q transposed + scaled
        int qr = t >> 4;
        int d0 = (t & 15) * 4;
        #pragma unroll
        for (int rep = 0; rep < 4; ++rep) {
            int q = qr + rep * 16;
            float4 v = *(const float4*)(Q + base + (size_t)(c0 + q) * DIM + d0);
            Qt[d0 + 0][q] = v.x * 0.125f;
            Qt[d0 + 1][q] = v.y * 0.125f;
            Qt[d0 + 2][q] = v.z * 0.125f;
            Qt[d0 + 3][q] = v.w * 0.125f;
        }
    }
    if (t < 64) { mrow[t] = -1e30f; lrow[t] = 0.f; }
    float o[4][4] = {};

    const int kbase0 = c0 - WIN;
    for (int tile = 0; tile < 9; ++tile) {
        const int kb = kbase0 + tile * 64;
        __syncthreads();   // prev PV done (and Qt/mrow visible on tile 0)
        {   // stage K (transposed) + V (natural)
            int kr = t >> 4;
            int d0 = (t & 15) * 4;
            #pragma unroll
            for (int rep = 0; rep < 4; ++rep) {
                int kk = kr + rep * 16;
                int kg = kb + kk;
                int kgc = min(max(kg, 0), SEQ - 1);
                float4 kv = *(const float4*)(Kb + base + (size_t)kgc * DIM + d0);
                Ktt[d0 + 0][kk] = kv.x; Ktt[d0 + 1][kk] = kv.y;
                Ktt[d0 + 2][kk] = kv.z; Ktt[d0 + 3][kk] = kv.w;
                *(float4*)&Vs[kk][d0] = *(const float4*)(Vb + base + (size_t)kgc * DIM + d0);
            }
        }
        __syncthreads();
        {   // S = Q^T K (outer product over dims), 4x4 micro-tile
            float s[4][4] = {};
            #pragma unroll 8
            for (int d = 0; d < 64; ++d) {
                float4 qv = *(const float4*)&Qt[d][ty * 4];
                float4 kv = *(const float4*)&Ktt[d][tx * 4];
                float qa[4] = {qv.x, qv.y, qv.z, qv.w};
                float ka[4] = {kv.x, kv.y, kv.z, kv.w};
                #pragma unroll
                for (int i = 0; i < 4; ++i)
                    #pragma unroll
                    for (int j = 0; j < 4; ++j)
                        s[i][j] += qa[i] * ka[j];
            }
            #pragma unroll
            for (int i = 0; i < 4; ++i) {
                float4 sv = {s[i][0], s[i][1], s[i][2], s[i][3]};
                *(float4*)&Sb[ty * 4 + i][tx * 4] = sv;
            }
        }
        __syncthreads();
        {   // online softmax: thread (r = t>>2, sub = t&3) owns 16 keys of row r
            int r = t >> 2, sub = t & 3;
            int qg = c0 + r;
            float sv[16];
            unsigned msk = 0;
            float mloc = -1e30f;
            #pragma unroll
            for (int cc = 0; cc < 4; ++cc) {
                float4 s4 = *(const float4*)&Sb[r][sub * 16 + cc * 4];
                float tmp[4] = {s4.x, s4.y, s4.z, s4.w};
                #pragma unroll
                for (int j = 0; j < 4; ++j) {
                    int kg = kb + sub * 16 + cc * 4 + j;
                    bool ok = (kg >= 0) && (kg < SEQ) && (kg >= qg - WIN) && (kg <= qg + WIN);
                    sv[cc * 4 + j] = tmp[j];
                    if (ok) { msk |= 1u << (cc * 4 + j); mloc = fmaxf(mloc, tmp[j]); }
                }
            }
            mloc = fmaxf(mloc, __shfl_xor(mloc, 1));
            mloc = fmaxf(mloc, __shfl_xor(mloc, 2));
            float mold = mrow[r];
            float mnew = fmaxf(mold, mloc);
            float lsum = 0.f;
            #pragma unroll
            for (int j2 = 0; j2 < 16; ++j2) {
                float ee = ((msk >> j2) & 1u) ? __expf(sv[j2] - mnew) : 0.f;
                lsum += ee;
                Pt[sub * 16 + j2][r] = ee;
            }
            lsum += __shfl_xor(lsum, 1);
            lsum += __shfl_xor(lsum, 2);
            if (sub == 0) {
                float alpha = __expf(mold - mnew);
                arow[r] = alpha;
                mrow[r] = mnew;
                lrow[r] = lrow[r] * alpha + lsum;
            }
        }
        __syncthreads();
        {   // PV accumulate
            float av[4];
            #pragma unroll
            for (int i = 0; i < 4; ++i) av[i] = arow[ty * 4 + i];
            #pragma unroll
            for (int i = 0; i < 4; ++i)
                #pragma unroll
                for (int j = 0; j < 4; ++j) o[i][j] *= av[i];
            #pragma unroll 8
            for (int k = 0; k < 64; ++k) {
                float4 pv = *(const float4*)&Pt[k][ty * 4];
                float4 vv = *(const float4*)&Vs[k][tx * 4];
                float pa[4] = {pv.x, pv.y, pv.z, pv.w};
                float va[4] = {vv.x, vv.y, vv.z, vv.w};
                #pragma unroll
                for (int i = 0; i < 4; ++i)
                    #pragma unroll
                    for (int j = 0; j < 4; ++j)
                        o[i][j] += pa[i] * va[j];
            }
        }
    }
    #pragma unroll
    for (int i = 0; i < 4; ++i) {
        float linv = 1.f / lrow[ty * 4 + i];
        float4 ov = {o[i][0] * linv, o[i][1] * linv, o[i][2] * linv, o[i][3] * linv};
        *(float4*)&CTX[base + (size_t)(c0 + ty * 4 + i) * DIM + tx * 4] = ov;
    }
}

// ---------------- LSTM gates ----------------
__global__ __launch_bounds__(256) void lstm_gate_k(const float* __restrict__ zx,
                                                   const float* __restrict__ zh,
                                                   const float* __restrict__ cin,
                                                   float* __restrict__ hout,
                                                   float* __restrict__ cout,
                                                   float* __restrict__ hcopy) {
    int idx = blockIdx.x * 256 + threadIdx.x;
    int n = idx >> 8, u = idx & 255;
    size_t zb = (size_t)n * 1024;
    float zi = zx[zb + u], zf = zx[zb + 256 + u], zg = zx[zb + 512 + u], zo = zx[zb + 768 + u];
    if (zh) { zi += zh[zb + u]; zf += zh[zb + 256 + u]; zg += zh[zb + 512 + u]; zo += zh[zb + 768 + u]; }
    float cp = cin ? cin[idx] : 0.f;
    float c = sigm(zf) * cp + sigm(zi) * tanhf(zg);
    float hv = sigm(zo) * tanhf(c);
    hout[(size_t)n * 512 + u] = hv;
    cout[idx] = c;
    hcopy[idx] = hv;
}

// ---------------- attention pooling tail ----------------
__global__ __launch_bounds__(256) void energy_k(const float* __restrict__ E1,
                                                const float* __restrict__ W2,
                                                const float* __restrict__ b2,
                                                float* __restrict__ EN) {
    int w = threadIdx.x >> 6, lane = threadIdx.x & 63;
    int r = blockIdx.x * 4 + w;
    float v = E1[(size_t)r * 64 + lane] * W2[lane];
    v = wred_sum(v);
    if (lane == 0) EN[r] = v + b2[0];
}

__global__ __launch_bounds__(256) void softmax_k(const float* __restrict__ EN,
                                                 float* __restrict__ WTS) {
    __shared__ float red[256];
    int b = blockIdx.x, t = threadIdx.x;
    const float* e = EN + (size_t)b * SEQ;
    float x[8];
    float m = -1e30f;
    #pragma unroll
    for (int i = 0; i < 8; ++i) { x[i] = e[t + 256 * i]; m = fmaxf(m, x[i]); }
    m = block_max256(m, red);
    float s = 0.f;
    #pragma unroll
    for (int i = 0; i < 8; ++i) { x[i] = expf(x[i] - m); s += x[i]; }
    s = block_sum256(s, red);
    float inv = 1.f / s;
    #pragma unroll
    for (int i = 0; i < 8; ++i) WTS[(size_t)b * SEQ + t + 256 * i] = x[i] * inv;
}

__global__ __launch_bounds__(512) void pooled_k(const float* __restrict__ WTS,
                                                const float* __restrict__ L1,
                                                float* __restrict__ P) {
    int b = blockIdx.x, d = threadIdx.x;
    const float* Lb = L1 + (size_t)b * SEQ * HID2;
    const float* wb = WTS + (size_t)b * SEQ;
    float acc = 0.f;
    for (int n = 0; n < SEQ; ++n) acc += wb[n] * Lb[(size_t)n * HID2 + d];
    P[b * HID2 + d] = acc;
}

// ---------------- tiny BiLSTM2 + tag head (single block) ----------------
__global__ __launch_bounds__(1024) void lstm2_k(const float* __restrict__ P,
                                                const float* __restrict__ Wih,
                                                const float* __restrict__ Whh,
                                                const float* __restrict__ bih,
                                                const float* __restrict__ bhh,
                                                const float* __restrict__ Wtag,
                                                const float* __restrict__ btag,
                                                float* __restrict__ out) {
    __shared__ float h[256], c[256], z[1024], flat2[1024], red[1024];
    int t = threadIdx.x;
    for (int dir = 0; dir < 2; ++dir) {
        if (t < 256) { h[t] = 0.f; c[t] = 0.f; }
        __syncthreads();
        for (int st = 0; st < 2; ++st) {
            int xt = (dir == 0) ? st : 1 - st;
            {
                int j = t;
                const float* wr = Wih + ((size_t)dir * 1024 + j) * HID2;
                const float* pr = P + xt * HID2;
                float acc = bih[dir * 1024 + j] + bhh[dir * 1024 + j];
                for (int k = 0; k < HID2; ++k) acc += pr[k] * wr[k];
                const float* wh = Whh + ((size_t)dir * 1024 + j) * HALF2;
                for (int k = 0; k < HALF2; ++k) acc += h[k] * wh[k];
                z[j] = acc;
            }
            __syncthreads();
            if (t < 256) {
                float zi = z[t], zf = z[256 + t], zg = z[512 + t], zo = z[768 + t];
                float cn = sigm(zf) * c[t] + sigm(zi) * tanhf(zg);
                float hn = sigm(zo) * tanhf(cn);
                c[t] = cn;
                h[t] = hn;
                int oidx = (dir == 0) ? (st * 512 + t) : ((1 - st) * 512 + 256 + t);
                flat2[oidx] = hn;
            }
            __syncthreads();
        }
    }
    for (int b = 0; b < 2; ++b) {
        float v = (t < 512) ? flat2[b * 512 + t] * Wtag[t] : 0.f;
        red[t] = v; __syncthreads();
        for (int s = 512; s > 0; s >>= 1) { if (t < s) red[t] += red[t + s]; __syncthreads(); }
        if (t == 0) out[b] = red[0] + btag[0];
        __syncthreads();
    }
}

extern "C" void kernel_launch(void* const* d_in, const int* in_sizes, int n_in,
                              void* d_out, int out_size, void* d_ws, size_t ws_size,
                              hipStream_t stream) {
    (void)in_sizes; (void)n_in; (void)out_size; (void)ws_size;
    const int* sent = (const int*)d_in[0];
    const float* word_emb = (const float*)d_in[1];
    const float* pos_emb  = (const float*)d_in[2];
    const float* emb_ln_s = (const float*)d_in[3];
    const float* emb_ln_b = (const float*)d_in[4];
    const float* Wq = (const float*)d_in[5];
    const float* Wk = (const float*)d_in[6];
    const float* Wv = (const float*)d_in[7];
    const float* Wo = (const float*)d_in[8];
    const float* bq = (const float*)d_in[9];
    const float* bk = (const float*)d_in[10];
    const float* bv = (const float*)d_in[11];
    const float* bo = (const float*)d_in[12];
    const float* ln1_s = (const float*)d_in[13];
    const float* ln1_b = (const float*)d_in[14];
    const float* Wf1 = (const float*)d_in[15];
    const float* bf1 = (const float*)d_in[16];
    const float* Wf2 = (const float*)d_in[17];
    const float* bf2 = (const float*)d_in[18];
    const float* ln2_s = (const float*)d_in[19];
    const float* ln2_b = (const float*)d_in[20];
    const float* l1_Wih = (const float*)d_in[21];
    const float* l1_Whh = (const float*)d_in[22];
    const float* l1_bih = (const float*)d_in[23];
    const float* l1_bhh = (const float*)d_in[24];
    const float* pa_W1 = (const float*)d_in[25];
    const float* pa_b1 = (const float*)d_in[26];
    const float* pa_W2 = (const float*)d_in[27];
    const float* pa_b2 = (const float*)d_in[28];
    const float* l2_Wih = (const float*)d_in[29];
    const float* l2_Whh = (const float*)d_in[30];
    const float* l2_bih = (const float*)d_in[31];
    const float* l2_bhh = (const float*)d_in[32];
    const float* Wtag = (const float*)d_in[33];
    const float* btag = (const float*)d_in[34];

    float* ws = (float*)d_ws;
    const size_t NX = (size_t)BB * SEQ * DIM;      // 3145728
    float* X1  = ws;
    float* Qb  = ws + NX * 1;
    float* X   = ws + NX * 2;
    float* Kbf = ws + NX * 3;
    float* Vbf = ws + NX * 4;
    float* CTX = ws + NX * 5;
    float* FH  = ws + NX * 2;                      // overlays X..CTX during FF
    float* XZF  = ws + NX * 3;                     // 4096x1024
    float* XZB  = XZF + (size_t)4096 * 1024;
    float* TMPZ = ws;                              // 2048x1024
    float* L1O  = TMPZ + (size_t)2048 * 1024;      // 2x2048x512
    float* HPV  = L1O + (size_t)2 * 2048 * 512;
    float* CST  = HPV + (size_t)2048 * 256;
    float* E1   = CST + (size_t)2048 * 256;
    float* ENG  = E1 + (size_t)4096 * 64;
    float* WTS  = ENG + 4096;
    float* PLD  = WTS + 4096;

    const int M = BB * SEQ;  // 4096

    embed_k<<<M, 256, 0, stream>>>(sent, word_emb, pos_emb, emb_ln_s, emb_ln_b, X);

    for (int l = 0; l < NL; ++l) {
        const float* Wq_l = Wq + (size_t)l * DIM * DIM;
        const float* Wk_l = Wk + (size_t)l * DIM * DIM;
        const float* Wv_l = Wv + (size_t)l * DIM * DIM;
        const float* Wo_l = Wo + (size_t)l * DIM * DIM;
        const float* Wf1_l = Wf1 + (size_t)l * DIM * FFD;
        const float* Wf2_l = Wf2 + (size_t)l * FFD * DIM;

        {   // fused QKV
            GP g = {{Wq_l, Wk_l, Wv_l},
                    {bq + l * DIM, bk + l * DIM, bv + l * DIM},
                    {nullptr, nullptr, nullptr},
                    {Qb, Kbf, Vbf}};
            gemm_mfma<0, 0><<<dim3(DIM / 128, M / 128, 3), 256, 0, stream>>>(X, g, M, DIM, DIM);
        }

        attn2_k<<<dim3(SEQ / 64, NH, BB), 256, 0, stream>>>(Qb, Kbf, Vbf, CTX);

        {   // output projection
            GP g = {{Wo_l, nullptr, nullptr},
                    {bo + l * DIM, nullptr, nullptr},
                    {nullptr, nullptr, nullptr},
                    {Qb, nullptr, nullptr}};
            gemm_mfma<0, 0><<<dim3(DIM / 128, M / 128, 1), 256, 0, stream>>>(CTX, g, M, DIM, DIM);
        }
        resln_k<<<M, 256, 0, stream>>>(X, Qb, ln1_s + l * DIM, ln1_b + l * DIM, X1);

        {   // FF1 + gelu
            GP g = {{Wf1_l, nullptr, nullptr},
                    {bf1 + l * FFD, nullptr, nullptr},
                    {nullptr, nullptr, nullptr},
                    {FH, nullptr, nullptr}};
            gemm_mfma<0, 1><<<dim3(FFD / 128, M / 128, 1), 256, 0, stream>>>(X1, g, M, FFD, DIM);
        }
        {   // FF2
            GP g = {{Wf2_l, nullptr, nullptr},
                    {bf2 + l * DIM, nullptr, nullptr},
                    {nullptr, nullptr, nullptr},
                    {Qb, nullptr, nullptr}};
            gemm_mfma<0, 0><<<dim3(DIM / 128, M / 128, 1), 256, 0, stream>>>(FH, g, M, DIM, FFD);
        }
        resln_k<<<M, 256, 0, stream>>>(X1, Qb, ln2_s + l * DIM, ln2_b + l * DIM, X);
    }

    // ---- BiLSTM over the 2-step batch axis (fused both dirs, z=2) ----
    {
        GP g = {{l1_Wih, l1_Wih + (size_t)1024 * DIM, nullptr},
                {l1_bih, l1_bih + 1024, nullptr},
                {l1_bhh, l1_bhh + 1024, nullptr},
                {XZF, XZB, nullptr}};
        gemm_mfma<1, 0><<<dim3(1024 / 128, M / 128, 2), 256, 0, stream>>>(X, g, M, 1024, DIM);
    }

    // forward dir
    lstm_gate_k<<<2048, 256, 0, stream>>>(XZF, nullptr, nullptr, L1O + 0, CST, HPV);
    {
        GP g = {{l1_Whh, nullptr, nullptr}, {nullptr, nullptr, nullptr},
                {nullptr, nullptr, nullptr}, {TMPZ, nullptr, nullptr}};
        gemm_mfma<1, 0><<<dim3(1024 / 128, 2048 / 128, 1), 256, 0, stream>>>(HPV, g, 2048, 1024, 256);
    }
    lstm_gate_k<<<2048, 256, 0, stream>>>(XZF + (size_t)2048 * 1024, TMPZ, CST, L1O + (size_t)1 * 2048 * 512, CST, HPV);
    // backward dir
    lstm_gate_k<<<2048, 256, 0, stream>>>(XZB + (size_t)2048 * 1024, nullptr, nullptr, L1O + (size_t)1 * 2048 * 512 + 256, CST, HPV);
    {
        GP g = {{l1_Whh + (size_t)1024 * 256, nullptr, nullptr}, {nullptr, nullptr, nullptr},
                {nullptr, nullptr, nullptr}, {TMPZ, nullptr, nullptr}};
        gemm_mfma<1, 0><<<dim3(1024 / 128, 2048 / 128, 1), 256, 0, stream>>>(HPV, g, 2048, 1024, 256);
    }
    lstm_gate_k<<<2048, 256, 0, stream>>>(XZB, TMPZ, CST, L1O + 256, CST, HPV);

    // ---- attention pooling ----
    gemm_k<0, 2><<<dim3(1, M / 64), 256, 0, stream>>>(L1O, pa_W1, pa_b1, nullptr, E1, M, 64, HID2);
    energy_k<<<M / 4, 256, 0, stream>>>(E1, pa_W2, pa_b2, ENG);
    softmax_k<<<BB, 256, 0, stream>>>(ENG, WTS);
    pooled_k<<<BB, 512, 0, stream>>>(WTS, L1O, PLD);

    // ---- tiny BiLSTM2 + head ----
    lstm2_k<<<1, 1024, 0, stream>>>(PLD, l2_Wih, l2_Whh, l2_bih, l2_bhh, Wtag, btag, (float*)d_out);
}